// Round 4
// baseline (4876.240 us; speedup 1.0000x reference)
//
#include <hip/hip_runtime.h>
#include <hip/hip_bf16.h>

typedef __hip_bfloat16 bf16;
typedef __bf16 bf16x8 __attribute__((ext_vector_type(8)));
typedef float f32x4 __attribute__((ext_vector_type(4)));

#define ROWS   32
#define HID    1024
#define PATH   256
#define KIN    1280   // HID + PATH
#define NSTEP  50
#define IP     1288   // inp LDS pitch (bf16): 1280 + 8 pad
#define TP     1032   // th  LDS pitch: 1024 + 8 pad
#define SMEM_BYTES ((ROWS*IP + ROWS*TP) * 2)

__device__ __forceinline__ f32x4 mfma16(bf16x8 a, bf16x8 b, f32x4 c) {
    return __builtin_amdgcn_mfma_f32_16x16x32_bf16(a, b, c, 0, 0, 0);
}

__device__ __forceinline__ float tanh_fast(float x) {
    float e = __expf(2.0f * x);
    return 1.0f - 2.0f / (e + 1.0f);   // saturates, no NaN for finite x
}

__device__ __forceinline__ bf16x8 ldcvt8(const float* __restrict__ p) {
    f32x4 lo = *(const f32x4*)p;
    f32x4 hi = *(const f32x4*)(p + 4);
    bf16x8 r;
    #pragma unroll
    for (int j = 0; j < 4; j++) { r[j] = (__bf16)lo[j]; r[4 + j] = (__bf16)hi[j]; }
    return r;
}

// ---- pack f32 W[K][N] into bf16 MFMA B-fragment-linear layout ----
// fragment (kb, nb) = 1KB: lane l (lm=l&15, lq=l>>4) holds W[kb*32+lq*8+j][nb*16+lm]
// dst elem index: ((kb * (N/16) + nb) * 64 + l) * 8 + j
__global__ void pack_frag(const float* __restrict__ src, bf16* __restrict__ dst, int N) {
    int kb = blockIdx.x, nb = blockIdx.y, l = threadIdx.x;
    int lm = l & 15, lq = l >> 4;
    bf16x8 v;
    #pragma unroll
    for (int j = 0; j < 8; j++)
        v[j] = __float2bfloat16(src[(size_t)(kb * 32 + lq * 8 + j) * N + nb * 16 + lm]);
    *(bf16x8*)(dst + ((size_t)(kb * gridDim.y + nb) * 64 + l) * 8) = v;
}

// ---- 32 x 64-col GEMM slice: acc[2][4] += lds_A(32 rows) @ Wp cols [wave*64, +64) ----
// Wp packed with 64 fragments per kb row (N=1024).
template<int KB>
__device__ __forceinline__ void gemm4(const bf16* __restrict__ lds, int pitch,
                                      const bf16* __restrict__ Wp,
                                      int wave, int lane, f32x4 (&acc)[2][4]) {
    const int lm = lane & 15, lq = lane >> 4;
    #pragma unroll 2
    for (int kb = 0; kb < KB; kb++) {
        const bf16* wp = Wp + (((size_t)kb * 64 + wave * 4) * 64 + lane) * 8;
        bf16x8 w[4];
        #pragma unroll
        for (int nt = 0; nt < 4; nt++) w[nt] = *(const bf16x8*)(wp + nt * 512);
        bf16x8 a0 = *(const bf16x8*)(lds + lm * pitch + kb * 32 + lq * 8);
        bf16x8 a1 = *(const bf16x8*)(lds + (16 + lm) * pitch + kb * 32 + lq * 8);
        #pragma unroll
        for (int nt = 0; nt < 4; nt++) {
            acc[0][nt] = mfma16(a0, w[nt], acc[0][nt]);
            acc[1][nt] = mfma16(a1, w[nt], acc[1][nt]);
        }
    }
}

// ---------------- persistent fused CDE kernel ----------------
// 256 wgs (1/CU), 1024 threads = 16 waves (4/SIMD for latency hiding).
// Each wg owns 32 batch rows; z persists in f32 registers in MFMA C-layout.
// Wave w computes cols [64w, 64w+64) of the 1024-col GEMMs and cols
// [16w, 16w+16) of the 256-col g GEMM.
__global__ __launch_bounds__(1024) void cde_main(
    const float* __restrict__ x0,  const float* __restrict__ b_pe, const float* __restrict__ b_hi,
    const float* __restrict__ b1v, const float* __restrict__ b2v,  const float* __restrict__ b_ro,
    const bf16* __restrict__ WpeP, const bf16* __restrict__ WhiP,
    const bf16* __restrict__ W1P,  const bf16* __restrict__ W2P, const bf16* __restrict__ WroP,
    float* __restrict__ out)
{
    extern __shared__ bf16 smem[];
    bf16* inp = smem;              // [32][IP]  cols 0..1023 = z, 1024..1279 = u_t
    bf16* th  = smem + ROWS * IP;  // [32][TP]

    const int tid  = threadIdx.x;
    const int wave = tid >> 6;     // 0..15
    const int lane = tid & 63;
    const int lm   = lane & 15;
    const int lq   = lane >> 4;
    const long row0 = (long)blockIdx.x * ROWS;

    f32x4 z[2][4];   // row = mt*16+lq*4+r, col = wave*64+nt*16+lm
    f32x4 g[2];      // col = wave*16+lm

    // ---- merged prologue: g = x0@W_pe + b_pe ; z = x0@W_hi + b_hi ----
    #pragma unroll
    for (int nt = 0; nt < 4; nt++) {
        float b = b_hi[wave * 64 + nt * 16 + lm];
        #pragma unroll
        for (int r = 0; r < 4; r++) { z[0][nt][r] = b; z[1][nt][r] = b; }
    }
    {
        float b = b_pe[wave * 16 + lm];
        #pragma unroll
        for (int r = 0; r < 4; r++) { g[0][r] = b; g[1][r] = b; }
    }
    for (int kb = 0; kb < HID / 32; kb++) {
        bf16x8 a0 = ldcvt8(x0 + (row0 +      lm) * HID + kb * 32 + lq * 8);
        bf16x8 a1 = ldcvt8(x0 + (row0 + 16 + lm) * HID + kb * 32 + lq * 8);
        const bf16* wp = WhiP + (((size_t)kb * 64 + wave * 4) * 64 + lane) * 8;
        #pragma unroll
        for (int nt = 0; nt < 4; nt++) {
            bf16x8 bb = *(const bf16x8*)(wp + nt * 512);
            z[0][nt] = mfma16(a0, bb, z[0][nt]);
            z[1][nt] = mfma16(a1, bb, z[1][nt]);
        }
        bf16x8 pb = *(const bf16x8*)(WpeP + (((size_t)kb * 16 + wave) * 64 + lane) * 8);
        g[0] = mfma16(a0, pb, g[0]);
        g[1] = mfma16(a1, pb, g[1]);
    }

    const float DT = 1.0f / (float)NSTEP;

    // ---- 50 fused steps ----
    for (int s = 0; s < NSTEP; s++) {
        float t = DT * (float)(s + 1);

        // A-phase: refresh bf16 inp = [z | t*g] from registers
        #pragma unroll
        for (int mt = 0; mt < 2; mt++)
            #pragma unroll
            for (int nt = 0; nt < 4; nt++)
                #pragma unroll
                for (int r = 0; r < 4; r++)
                    inp[(mt * 16 + lq * 4 + r) * IP + wave * 64 + nt * 16 + lm] =
                        __float2bfloat16(z[mt][nt][r]);
        #pragma unroll
        for (int mt = 0; mt < 2; mt++)
            #pragma unroll
            for (int r = 0; r < 4; r++)
                inp[(mt * 16 + lq * 4 + r) * IP + HID + wave * 16 + lm] =
                    __float2bfloat16(t * g[mt][r]);
        __syncthreads();

        // B-phase: h = tanh(inp @ W1 + b1) -> th
        {
            f32x4 acc[2][4];
            #pragma unroll
            for (int nt = 0; nt < 4; nt++) {
                float b = b1v[wave * 64 + nt * 16 + lm];
                #pragma unroll
                for (int r = 0; r < 4; r++) { acc[0][nt][r] = b; acc[1][nt][r] = b; }
            }
            gemm4<KIN / 32>(inp, IP, W1P, wave, lane, acc);
            #pragma unroll
            for (int mt = 0; mt < 2; mt++)
                #pragma unroll
                for (int nt = 0; nt < 4; nt++)
                    #pragma unroll
                    for (int r = 0; r < 4; r++)
                        th[(mt * 16 + lq * 4 + r) * TP + wave * 64 + nt * 16 + lm] =
                            __float2bfloat16(tanh_fast(acc[mt][nt][r]));
        }
        __syncthreads();

        // C-phase: dz = th @ W2 + b2 ; z += dt*dz
        {
            f32x4 acc[2][4];
            #pragma unroll
            for (int nt = 0; nt < 4; nt++) {
                float b = b2v[wave * 64 + nt * 16 + lm];
                #pragma unroll
                for (int r = 0; r < 4; r++) { acc[0][nt][r] = b; acc[1][nt][r] = b; }
            }
            gemm4<HID / 32>(th, TP, W2P, wave, lane, acc);
            #pragma unroll
            for (int mt = 0; mt < 2; mt++)
                #pragma unroll
                for (int nt = 0; nt < 4; nt++)
                    #pragma unroll
                    for (int r = 0; r < 4; r++)
                        z[mt][nt][r] += DT * acc[mt][nt][r];
        }
        // no barrier here: a wave reaches the next A->B barrier only after finishing
        // its own C-phase, so all th reads are complete before any th write of the
        // next iteration (which happens after that barrier).
    }

    // ---- epilogue: out = z @ W_ro + b_ro (f32 store) ----
    #pragma unroll
    for (int mt = 0; mt < 2; mt++)
        #pragma unroll
        for (int nt = 0; nt < 4; nt++)
            #pragma unroll
            for (int r = 0; r < 4; r++)
                inp[(mt * 16 + lq * 4 + r) * IP + wave * 64 + nt * 16 + lm] =
                    __float2bfloat16(z[mt][nt][r]);
    __syncthreads();
    {
        f32x4 acc[2][4];
        #pragma unroll
        for (int nt = 0; nt < 4; nt++) {
            float b = b_ro[wave * 64 + nt * 16 + lm];
            #pragma unroll
            for (int r = 0; r < 4; r++) { acc[0][nt][r] = b; acc[1][nt][r] = b; }
        }
        gemm4<HID / 32>(inp, IP, WroP, wave, lane, acc);
        #pragma unroll
        for (int mt = 0; mt < 2; mt++)
            #pragma unroll
            for (int nt = 0; nt < 4; nt++)
                #pragma unroll
                for (int r = 0; r < 4; r++)
                    out[(row0 + mt * 16 + lq * 4 + r) * HID + wave * 64 + nt * 16 + lm] =
                        acc[mt][nt][r];
    }
}

extern "C" void kernel_launch(void* const* d_in, const int* in_sizes, int n_in,
                              void* d_out, int out_size, void* d_ws, size_t ws_size,
                              hipStream_t stream) {
    (void)in_sizes; (void)n_in; (void)out_size; (void)ws_size;
    const float* x0  = (const float*)d_in[0];
    const float* Wpe = (const float*)d_in[1];
    const float* bpe = (const float*)d_in[2];
    const float* Whi = (const float*)d_in[3];
    const float* bhi = (const float*)d_in[4];
    const float* W1  = (const float*)d_in[5];
    const float* b1  = (const float*)d_in[6];
    const float* W2  = (const float*)d_in[7];
    const float* b2  = (const float*)d_in[8];
    const float* Wro = (const float*)d_in[9];
    const float* bro = (const float*)d_in[10];

    bf16* ws   = (bf16*)d_ws;
    bf16* WpeP = ws;                         // 256*1024
    bf16* WhiP = WpeP + 256 * 1024;          // 1024*1024
    bf16* W1P  = WhiP + 1024 * 1024;         // 1280*1024
    bf16* W2P  = W1P  + 1280 * 1024;         // 1024*1024
    bf16* WroP = W2P  + 1024 * 1024;         // 1024*1024

    hipLaunchKernelGGL(pack_frag, dim3(1024 / 32, 256 / 16), dim3(64), 0, stream, Wpe, WpeP, 256);
    hipLaunchKernelGGL(pack_frag, dim3(1024 / 32, 1024 / 16), dim3(64), 0, stream, Whi, WhiP, 1024);
    hipLaunchKernelGGL(pack_frag, dim3(1280 / 32, 1024 / 16), dim3(64), 0, stream, W1, W1P, 1024);
    hipLaunchKernelGGL(pack_frag, dim3(1024 / 32, 1024 / 16), dim3(64), 0, stream, W2, W2P, 1024);
    hipLaunchKernelGGL(pack_frag, dim3(1024 / 32, 1024 / 16), dim3(64), 0, stream, Wro, WroP, 1024);

    hipFuncSetAttribute((const void*)cde_main,
                        hipFuncAttributeMaxDynamicSharedMemorySize, SMEM_BYTES);
    hipLaunchKernelGGL(cde_main, dim3(8192 / ROWS), dim3(1024), SMEM_BYTES, stream,
                       x0, bpe, bhi, b1, b2, bro, WpeP, WhiP, W1P, W2P, WroP,
                       (float*)d_out);
}

// Round 5
// 3145.155 us; speedup vs baseline: 1.5504x; 1.5504x over previous
//
#include <hip/hip_runtime.h>
#include <hip/hip_bf16.h>

typedef __hip_bfloat16 bf16;
typedef __bf16 bf16x8 __attribute__((ext_vector_type(8)));
typedef float f32x4 __attribute__((ext_vector_type(4)));

#define ROWS   32
#define HID    1024
#define PATH   256
#define NSTEP  50
#define P      1032   // LDS pitch (bf16) for inp(z) and th: 1024 + 8 -> uniform bank spread
#define SMEM_BYTES (2 * ROWS * P * 2)   // inp + th, bf16

__device__ __forceinline__ f32x4 mfma16(bf16x8 a, bf16x8 b, f32x4 c) {
    return __builtin_amdgcn_mfma_f32_16x16x32_bf16(a, b, c, 0, 0, 0);
}

__device__ __forceinline__ float tanh_fast(float x) {
    float e = __expf(2.0f * x);
    return 1.0f - 2.0f / (e + 1.0f);   // saturates, no NaN for finite x
}

__device__ __forceinline__ bf16x8 ldcvt8(const float* __restrict__ p) {
    f32x4 lo = *(const f32x4*)p;
    f32x4 hi = *(const f32x4*)(p + 4);
    bf16x8 r;
    #pragma unroll
    for (int j = 0; j < 4; j++) { r[j] = (__bf16)lo[j]; r[4 + j] = (__bf16)hi[j]; }
    return r;
}

// ---- pack f32 W[K][N] into bf16 MFMA B-fragment-linear layout ----
// fragment (kb, nb) = 1KB: lane l (lm=l&15, lq=l>>4) holds W[kb*32+lq*8+j][nb*16+lm]
__global__ void pack_frag(const float* __restrict__ src, bf16* __restrict__ dst, int N) {
    int kb = blockIdx.x, nb = blockIdx.y, l = threadIdx.x;
    int lm = l & 15, lq = l >> 4;
    bf16x8 v;
    #pragma unroll
    for (int j = 0; j < 8; j++)
        v[j] = __float2bfloat16(src[(size_t)(kb * 32 + lq * 8 + j) * N + nb * 16 + lm]);
    *(bf16x8*)(dst + ((size_t)(kb * gridDim.y + nb) * 64 + l) * 8) = v;
}

// ---- 32 x 64-col GEMM slice with rotated K-loop (per-CU de-lockstep) ----
// acc[2][4] += lds_A(32 rows, pitch P) @ Wp cols [wave*64, +64); KB k-blocks of 32.
template<int KB>
__device__ __forceinline__ void gemm4r(const bf16* __restrict__ lds,
                                       const bf16* __restrict__ Wp,
                                       int wave, int lane, int rot, f32x4 (&acc)[2][4]) {
    const int lm = lane & 15, lq = lane >> 4;
    #pragma unroll 2
    for (int kb = 0; kb < KB; kb++) {
        int kbr = kb + rot; if (kbr >= KB) kbr -= KB;    // scalar (wg-uniform)
        const bf16* wp = Wp + (((size_t)kbr * 64 + wave * 4) * 64 + lane) * 8;
        bf16x8 w[4];
        #pragma unroll
        for (int nt = 0; nt < 4; nt++) w[nt] = *(const bf16x8*)(wp + nt * 512);
        bf16x8 a0 = *(const bf16x8*)(lds + lm * P + kbr * 32 + lq * 8);
        bf16x8 a1 = *(const bf16x8*)(lds + (16 + lm) * P + kbr * 32 + lq * 8);
        #pragma unroll
        for (int nt = 0; nt < 4; nt++) {
            acc[0][nt] = mfma16(a0, w[nt], acc[0][nt]);
            acc[1][nt] = mfma16(a1, w[nt], acc[1][nt]);
        }
    }
}

// ---------------- persistent fused CDE kernel ----------------
// 256 wgs (1/CU), 1024 threads = 16 waves. Each wg owns 32 batch rows; z persists
// in f32 registers (MFMA C-layout). Wave w computes cols [64w,64w+64).
// u-path folded: c_u = g @ W1u computed once; per-step GEMM1 acc init = b1 + t*c_u.
__global__ __launch_bounds__(1024) void cde_main(
    const float* __restrict__ x0,  const float* __restrict__ b_pe, const float* __restrict__ b_hi,
    const float* __restrict__ b1v, const float* __restrict__ b2v,  const float* __restrict__ b_ro,
    const bf16* __restrict__ WpeP, const bf16* __restrict__ WhiP,
    const bf16* __restrict__ W1zP, const bf16* __restrict__ W1uP,
    const bf16* __restrict__ W2P,  const bf16* __restrict__ WroP,
    float* __restrict__ out)
{
    extern __shared__ bf16 smem[];
    bf16* inp = smem;              // [32][P]  z staging (cols 0..1023); prologue: g staging
    bf16* th  = smem + ROWS * P;   // [32][P]

    const int tid  = threadIdx.x;
    const int wave = tid >> 6;     // 0..15
    const int lane = tid & 63;
    const int lm   = lane & 15;
    const int lq   = lane >> 4;
    const int rot  = (blockIdx.x >> 3) & 31;   // distinct per CU within an XCD
    const long row0 = (long)blockIdx.x * ROWS;

    f32x4 z[2][4];    // row = mt*16+lq*4+r, col = wave*64+nt*16+lm
    f32x4 g[2];       // col = wave*16+lm
    f32x4 c_u[2][4];  // g @ W1u, same layout as z

    // ---- merged prologue: g = x0@W_pe + b_pe ; z = x0@W_hi + b_hi ----
    #pragma unroll
    for (int nt = 0; nt < 4; nt++) {
        float b = b_hi[wave * 64 + nt * 16 + lm];
        #pragma unroll
        for (int r = 0; r < 4; r++) { z[0][nt][r] = b; z[1][nt][r] = b; }
    }
    {
        float b = b_pe[wave * 16 + lm];
        #pragma unroll
        for (int r = 0; r < 4; r++) { g[0][r] = b; g[1][r] = b; }
    }
    for (int kb = 0; kb < HID / 32; kb++) {
        int kbr = kb + rot; if (kbr >= 32) kbr -= 32;
        bf16x8 a0 = ldcvt8(x0 + (row0 +      lm) * HID + kbr * 32 + lq * 8);
        bf16x8 a1 = ldcvt8(x0 + (row0 + 16 + lm) * HID + kbr * 32 + lq * 8);
        const bf16* wp = WhiP + (((size_t)kbr * 64 + wave * 4) * 64 + lane) * 8;
        #pragma unroll
        for (int nt = 0; nt < 4; nt++) {
            bf16x8 bb = *(const bf16x8*)(wp + nt * 512);
            z[0][nt] = mfma16(a0, bb, z[0][nt]);
            z[1][nt] = mfma16(a1, bb, z[1][nt]);
        }
        bf16x8 pb = *(const bf16x8*)(WpeP + (((size_t)kbr * 16 + wave) * 64 + lane) * 8);
        g[0] = mfma16(a0, pb, g[0]);
        g[1] = mfma16(a1, pb, g[1]);
    }

    // ---- c_u = g @ W1u (once) ----
    // stage g (C-layout regs -> LDS A-layout), 256 cols total
    #pragma unroll
    for (int mt = 0; mt < 2; mt++)
        #pragma unroll
        for (int r = 0; r < 4; r++)
            inp[(mt * 16 + lq * 4 + r) * P + wave * 16 + lm] = __float2bfloat16(g[mt][r]);
    __syncthreads();
    #pragma unroll
    for (int mt = 0; mt < 2; mt++)
        #pragma unroll
        for (int nt = 0; nt < 4; nt++)
            #pragma unroll
            for (int r = 0; r < 4; r++) c_u[mt][nt][r] = 0.0f;
    for (int kb = 0; kb < PATH / 32; kb++) {
        const bf16* wp = W1uP + (((size_t)kb * 64 + wave * 4) * 64 + lane) * 8;
        bf16x8 a0 = *(const bf16x8*)(inp + lm * P + kb * 32 + lq * 8);
        bf16x8 a1 = *(const bf16x8*)(inp + (16 + lm) * P + kb * 32 + lq * 8);
        #pragma unroll
        for (int nt = 0; nt < 4; nt++) {
            bf16x8 bb = *(const bf16x8*)(wp + nt * 512);
            c_u[0][nt] = mfma16(a0, bb, c_u[0][nt]);
            c_u[1][nt] = mfma16(a1, bb, c_u[1][nt]);
        }
    }
    __syncthreads();

    // hoist biases
    float b1r[4], b2r[4];
    #pragma unroll
    for (int nt = 0; nt < 4; nt++) {
        b1r[nt] = b1v[wave * 64 + nt * 16 + lm];
        b2r[nt] = b2v[wave * 64 + nt * 16 + lm];
    }

    const float DT = 1.0f / (float)NSTEP;

    // ---- 50 fused steps ----
    for (int s = 0; s < NSTEP; s++) {
        float t = DT * (float)(s + 1);

        // A-phase: refresh bf16 z staging
        #pragma unroll
        for (int mt = 0; mt < 2; mt++)
            #pragma unroll
            for (int nt = 0; nt < 4; nt++)
                #pragma unroll
                for (int r = 0; r < 4; r++)
                    inp[(mt * 16 + lq * 4 + r) * P + wave * 64 + nt * 16 + lm] =
                        __float2bfloat16(z[mt][nt][r]);
        __syncthreads();

        // B-phase: h = tanh(z @ W1z + t*c_u + b1) -> th
        {
            f32x4 acc[2][4];
            #pragma unroll
            for (int mt = 0; mt < 2; mt++)
                #pragma unroll
                for (int nt = 0; nt < 4; nt++)
                    #pragma unroll
                    for (int r = 0; r < 4; r++)
                        acc[mt][nt][r] = fmaf(t, c_u[mt][nt][r], b1r[nt]);
            gemm4r<HID / 32>(inp, W1zP, wave, lane, rot, acc);
            #pragma unroll
            for (int mt = 0; mt < 2; mt++)
                #pragma unroll
                for (int nt = 0; nt < 4; nt++)
                    #pragma unroll
                    for (int r = 0; r < 4; r++)
                        th[(mt * 16 + lq * 4 + r) * P + wave * 64 + nt * 16 + lm] =
                            __float2bfloat16(tanh_fast(acc[mt][nt][r]));
        }
        __syncthreads();

        // C-phase: dz = th @ W2 + b2 ; z += dt*dz
        {
            f32x4 acc[2][4];
            #pragma unroll
            for (int nt = 0; nt < 4; nt++)
                #pragma unroll
                for (int r = 0; r < 4; r++) { acc[0][nt][r] = b2r[nt]; acc[1][nt][r] = b2r[nt]; }
            gemm4r<HID / 32>(th, W2P, wave, lane, rot, acc);
            #pragma unroll
            for (int mt = 0; mt < 2; mt++)
                #pragma unroll
                for (int nt = 0; nt < 4; nt++)
                    #pragma unroll
                    for (int r = 0; r < 4; r++)
                        z[mt][nt][r] += DT * acc[mt][nt][r];
        }
        // no barrier: next A-write (inp) is safe — all waves passed the last barrier
        // only after finishing their G1 inp-reads; th hazards separated by next barrier.
    }

    // ---- epilogue: out = z @ W_ro + b_ro (f32 store) ----
    #pragma unroll
    for (int mt = 0; mt < 2; mt++)
        #pragma unroll
        for (int nt = 0; nt < 4; nt++)
            #pragma unroll
            for (int r = 0; r < 4; r++)
                inp[(mt * 16 + lq * 4 + r) * P + wave * 64 + nt * 16 + lm] =
                    __float2bfloat16(z[mt][nt][r]);
    __syncthreads();
    {
        f32x4 acc[2][4];
        #pragma unroll
        for (int nt = 0; nt < 4; nt++) {
            float b = b_ro[wave * 64 + nt * 16 + lm];
            #pragma unroll
            for (int r = 0; r < 4; r++) { acc[0][nt][r] = b; acc[1][nt][r] = b; }
        }
        gemm4r<HID / 32>(inp, WroP, wave, lane, rot, acc);
        #pragma unroll
        for (int mt = 0; mt < 2; mt++)
            #pragma unroll
            for (int nt = 0; nt < 4; nt++)
                #pragma unroll
                for (int r = 0; r < 4; r++)
                    out[(row0 + mt * 16 + lq * 4 + r) * HID + wave * 64 + nt * 16 + lm] =
                        acc[mt][nt][r];
    }
}

extern "C" void kernel_launch(void* const* d_in, const int* in_sizes, int n_in,
                              void* d_out, int out_size, void* d_ws, size_t ws_size,
                              hipStream_t stream) {
    (void)in_sizes; (void)n_in; (void)out_size; (void)ws_size;
    const float* x0  = (const float*)d_in[0];
    const float* Wpe = (const float*)d_in[1];
    const float* bpe = (const float*)d_in[2];
    const float* Whi = (const float*)d_in[3];
    const float* bhi = (const float*)d_in[4];
    const float* W1  = (const float*)d_in[5];
    const float* b1  = (const float*)d_in[6];
    const float* W2  = (const float*)d_in[7];
    const float* b2  = (const float*)d_in[8];
    const float* Wro = (const float*)d_in[9];
    const float* bro = (const float*)d_in[10];

    bf16* ws   = (bf16*)d_ws;
    bf16* WpeP = ws;                          // 256*1024
    bf16* WhiP = WpeP + 256 * 1024;           // 1024*1024
    bf16* W1zP = WhiP + 1024 * 1024;          // 1024*1024 (W1 rows 0..1023)
    bf16* W1uP = W1zP + 1024 * 1024;          // 256*1024  (W1 rows 1024..1279)
    bf16* W2P  = W1uP + 256 * 1024;           // 1024*1024
    bf16* WroP = W2P  + 1024 * 1024;          // 1024*1024

    hipLaunchKernelGGL(pack_frag, dim3(1024 / 32, 256 / 16), dim3(64), 0, stream, Wpe, WpeP, 256);
    hipLaunchKernelGGL(pack_frag, dim3(1024 / 32, 1024 / 16), dim3(64), 0, stream, Whi, WhiP, 1024);
    hipLaunchKernelGGL(pack_frag, dim3(1024 / 32, 1024 / 16), dim3(64), 0, stream, W1, W1zP, 1024);
    hipLaunchKernelGGL(pack_frag, dim3(256 / 32, 1024 / 16), dim3(64), 0, stream,
                       W1 + (size_t)1024 * 1024, W1uP, 1024);
    hipLaunchKernelGGL(pack_frag, dim3(1024 / 32, 1024 / 16), dim3(64), 0, stream, W2, W2P, 1024);
    hipLaunchKernelGGL(pack_frag, dim3(1024 / 32, 1024 / 16), dim3(64), 0, stream, Wro, WroP, 1024);

    hipFuncSetAttribute((const void*)cde_main,
                        hipFuncAttributeMaxDynamicSharedMemorySize, SMEM_BYTES);
    hipLaunchKernelGGL(cde_main, dim3(8192 / ROWS), dim3(1024), SMEM_BYTES, stream,
                       x0, bpe, bhi, b1, b2, bro, WpeP, WhiP, W1zP, W1uP, W2P, WroP,
                       (float*)d_out);
}